// Round 1
// baseline (1086.737 us; speedup 1.0000x reference)
//
#include <hip/hip_runtime.h>
#include <hip/hip_bf16.h>

// SimpleBNN: out = sign(sign(sign(x)@sign(w1)T + b1) @ sign(w2)T + b2) @ w3T + b3
// Layers 1-2: exact ternary GEMM via bf16 MFMA (fp32 accum, sums <= 4096 -> exact).
// Layer 3: bf16 MFMA, w3 rounded to bf16 (error ~1e-3 << 6.5e-2 threshold).

typedef __attribute__((ext_vector_type(8))) short bf16x8;   // 8 bf16 in 4 VGPRs (per guide §3)
typedef __attribute__((ext_vector_type(4))) float f32x4;

#define BM 128
#define BN 128
#define BK 32

__device__ __forceinline__ void async_copy16(const void* g, void* l) {
  __builtin_amdgcn_global_load_lds(
      (const __attribute__((address_space(1))) void*)g,
      (__attribute__((address_space(3))) void*)l,
      16, 0, 0);
}

__device__ __forceinline__ float signf(float v) {
  return (v > 0.f) ? 1.f : ((v < 0.f) ? -1.f : 0.f);
}

// fp32 -> bf16 sign cast, 4 elems/thread
__global__ void sign_pack(const float* __restrict__ in, __hip_bfloat16* __restrict__ out, int n4) {
  int i = blockIdx.x * blockDim.x + threadIdx.x;
  if (i >= n4) return;
  float4 v = ((const float4*)in)[i];
  union { ushort4 u; __hip_bfloat16 h[4]; } o;
  o.h[0] = __float2bfloat16(signf(v.x));
  o.h[1] = __float2bfloat16(signf(v.y));
  o.h[2] = __float2bfloat16(signf(v.z));
  o.h[3] = __float2bfloat16(signf(v.w));
  ((ushort4*)out)[i] = o.u;
}

// w3 [1000,4096] fp32 -> [1024,4096] bf16, rows >= 1000 zero-filled
__global__ void w3_cast(const float* __restrict__ in, __hip_bfloat16* __restrict__ out, int rows_valid) {
  int i = blockIdx.x * blockDim.x + threadIdx.x;   // over 1024*4096/4
  int idx = i * 4;
  int row = idx >> 12;                              // 4096 cols
  union { ushort4 u; __hip_bfloat16 h[4]; } o;
  if (row < rows_valid) {
    float4 v = *(const float4*)(in + idx);          // idx == row*4096+col, contiguous
    o.h[0] = __float2bfloat16(v.x);
    o.h[1] = __float2bfloat16(v.y);
    o.h[2] = __float2bfloat16(v.z);
    o.h[3] = __float2bfloat16(v.w);
  } else {
    o.h[0] = o.h[1] = o.h[2] = o.h[3] = __float2bfloat16(0.f);
  }
  ((ushort4*)out)[i] = o.u;
}

// C = A @ B^T (+bias), A [M,K] bf16 row-major, B [N,K] bf16 row-major.
// m97 structure: 128x128 tile, BK=32, global_load_lds width=16, 4 waves x 4x4 MFMA tiles.
// EPI=0: Cb[m*ldc+n] = bf16(sign(acc + bias[n]))
// EPI=1: Cf[m*ldc+n] = acc + bias[n], guarded n < nvalid
template <int EPI>
__global__ __launch_bounds__(256)
void gemm_bt(const __hip_bfloat16* __restrict__ A,
             const __hip_bfloat16* __restrict__ B,
             const float* __restrict__ bias,
             __hip_bfloat16* __restrict__ Cb,
             float* __restrict__ Cf,
             int K, int ldc, int nvalid)
{
  __shared__ __hip_bfloat16 As[BM * BK];   // 8 KB, row-major [128][32], lane-order contiguous
  __shared__ __hip_bfloat16 Bs[BN * BK];   // 8 KB

  const int tid  = threadIdx.x;
  const int lane = tid & 63;
  const int wid  = tid >> 6;
  const int wy   = wid >> 1;   // m-half of the 128x128 tile
  const int wx   = wid & 1;    // n-half

  const int m0 = blockIdx.y * BM;
  const int n0 = blockIdx.x * BN;

  // staging: thread t stages 16B at row t>>2, k-col (t&3)*8, for t=tid and t=tid+256
  const int srow = tid >> 2;
  const int scol = (tid & 3) * 8;
  const __hip_bfloat16* Ag = A + (size_t)(m0 + srow) * K + scol;
  const __hip_bfloat16* Bg = B + (size_t)(n0 + srow) * K + scol;
  __hip_bfloat16* Asl  = As + tid * 8;          // lds dest = wave base + lane*16B (HW rule)
  __hip_bfloat16* Asl2 = As + (256 + tid) * 8;
  __hip_bfloat16* Bsl  = Bs + tid * 8;
  __hip_bfloat16* Bsl2 = Bs + (256 + tid) * 8;
  const size_t rowskip = (size_t)64 * K;

  f32x4 acc[4][4];
#pragma unroll
  for (int i = 0; i < 4; ++i)
#pragma unroll
    for (int j = 0; j < 4; ++j)
      acc[i][j] = (f32x4){0.f, 0.f, 0.f, 0.f};

  const int fr = lane & 15;         // row within 16-tile (A: m, B: n)
  const int fk = (lane >> 4) * 8;   // k offset of this lane's 8 contiguous elems

  for (int k0 = 0; k0 < K; k0 += BK) {
    async_copy16(Ag + k0, Asl);
    async_copy16(Ag + rowskip + k0, Asl2);
    async_copy16(Bg + k0, Bsl);
    async_copy16(Bg + rowskip + k0, Bsl2);
    __syncthreads();   // drains vmcnt -> staged data visible

    bf16x8 a[4], b[4];
#pragma unroll
    for (int i = 0; i < 4; ++i)
      a[i] = *(const bf16x8*)(As + (wy * 64 + i * 16 + fr) * BK + fk);   // ds_read_b128
#pragma unroll
    for (int j = 0; j < 4; ++j)
      b[j] = *(const bf16x8*)(Bs + (wx * 64 + j * 16 + fr) * BK + fk);

#pragma unroll
    for (int i = 0; i < 4; ++i)
#pragma unroll
      for (int j = 0; j < 4; ++j)
        acc[i][j] = __builtin_amdgcn_mfma_f32_16x16x32_bf16(a[i], b[j], acc[i][j], 0, 0, 0);
    __syncthreads();   // protect LDS from next iter's staging
  }

  // C/D layout (verified m89/m91): col = lane&15, row = (lane>>4)*4 + reg
  const int ccol = lane & 15;
  const int crow = (lane >> 4) * 4;
#pragma unroll
  for (int i = 0; i < 4; ++i) {
    const int m = m0 + wy * 64 + i * 16 + crow;
#pragma unroll
    for (int j = 0; j < 4; ++j) {
      const int n = n0 + wx * 64 + j * 16 + ccol;
      float bv;
      if (EPI == 0) bv = bias[n];
      else          bv = (n < nvalid) ? bias[n] : 0.f;
#pragma unroll
      for (int r = 0; r < 4; ++r) {
        float v = acc[i][j][r] + bv;
        if (EPI == 0) {
          Cb[(size_t)(m + r) * ldc + n] = __float2bfloat16(signf(v));
        } else {
          if (n < nvalid) Cf[(size_t)(m + r) * ldc + n] = v;
        }
      }
    }
  }
}

extern "C" void kernel_launch(void* const* d_in, const int* in_sizes, int n_in,
                              void* d_out, int out_size, void* d_ws, size_t ws_size,
                              hipStream_t stream) {
  const float* x  = (const float*)d_in[0];   // [8192,4096]
  const float* w1 = (const float*)d_in[1];   // [4096,4096]
  const float* b1 = (const float*)d_in[2];   // [4096]
  const float* w2 = (const float*)d_in[3];   // [4096,4096]
  const float* b2 = (const float*)d_in[4];   // [4096]
  const float* w3 = (const float*)d_in[5];   // [1000,4096]
  const float* b3 = (const float*)d_in[6];   // [1000]

  const int Mb = 8192, H = 4096, C = 1000, Cpad = 1024;

  // workspace layout (200 MB total):
  //   [0,64MB)    sx  = sign(x) bf16; reused as a2 after gemm1 (sx dead then)
  //   [64,96)     sw1
  //   [96,128)    sw2
  //   [128,136)   w3b (1024x4096 bf16, padded)
  //   [136,200)   a1
  char* ws = (char*)d_ws;
  __hip_bfloat16* sx  = (__hip_bfloat16*)(ws);
  __hip_bfloat16* sw1 = (__hip_bfloat16*)(ws + (size_t)67108864);
  __hip_bfloat16* sw2 = (__hip_bfloat16*)(ws + (size_t)100663296);
  __hip_bfloat16* w3b = (__hip_bfloat16*)(ws + (size_t)134217728);
  __hip_bfloat16* a1  = (__hip_bfloat16*)(ws + (size_t)142606336);
  __hip_bfloat16* a2  = sx;

  sign_pack<<<(Mb * H / 4 + 255) / 256, 256, 0, stream>>>(x,  sx,  Mb * H / 4);
  sign_pack<<<(H * H / 4 + 255) / 256, 256, 0, stream>>>(w1, sw1, H * H / 4);
  sign_pack<<<(H * H / 4 + 255) / 256, 256, 0, stream>>>(w2, sw2, H * H / 4);
  w3_cast<<<(Cpad * H / 4 + 255) / 256, 256, 0, stream>>>(w3, w3b, C);

  dim3 blk(256);
  // layer 1: a1 = sign(sign(x) @ sign(w1)^T + b1)   [exact]
  gemm_bt<0><<<dim3(H / BN, Mb / BM), blk, 0, stream>>>(sx, sw1, b1, a1, nullptr, H, H, H);
  // layer 2: a2 = sign(a1 @ sign(w2)^T + b2)        [exact, a1 ternary]
  gemm_bt<0><<<dim3(H / BN, Mb / BM), blk, 0, stream>>>(a1, sw2, b2, a2, nullptr, H, H, H);
  // layer 3: out = a2 @ w3^T + b3                    [bf16-rounded w3]
  gemm_bt<1><<<dim3(Cpad / BN, Mb / BM), blk, 0, stream>>>(a2, w3b, b3, nullptr, (float*)d_out, H, C, C);
}

// Round 2
// 937.215 us; speedup vs baseline: 1.1595x; 1.1595x over previous
//
#include <hip/hip_runtime.h>
#include <hip/hip_bf16.h>

// SimpleBNN: out = sign(sign(sign(x)@sign(w1)T) @ sign(w2)T) @ w3T + b3  (b1=b2=0 but handled)
// Layers 1-2: exact ternary GEMM via i8 MFMA (i32 accum, |sums| <= 4096 -> exact).
// Layer 3: bf16 MFMA (m97 structure), w3 rounded to bf16 (error ~1e-2 << 6.5e-2 threshold).

typedef __attribute__((ext_vector_type(8))) short bf16x8;   // 8 bf16 in 4 VGPRs
typedef __attribute__((ext_vector_type(4))) float f32x4;
typedef __attribute__((ext_vector_type(4))) int   i32x4;    // i8 MFMA A/B frag (16 bytes) and C/D

#define BM 128
#define BN 128
#define BK 32    // bf16 gemm k-tile
#define IBK 64   // i8 gemm k-tile

__device__ __forceinline__ void async_copy16(const void* g, void* l) {
  __builtin_amdgcn_global_load_lds(
      (const __attribute__((address_space(1))) void*)g,
      (__attribute__((address_space(3))) void*)l,
      16, 0, 0);
}

__device__ __forceinline__ float signf(float v) {
  return (v > 0.f) ? 1.f : ((v < 0.f) ? -1.f : 0.f);
}
__device__ __forceinline__ char sign8(float v) {
  return (v > 0.f) ? (char)1 : ((v < 0.f) ? (char)-1 : (char)0);
}

// fp32 -> i8 sign cast, 4 elems/thread (4B coalesced stores)
__global__ void sign_pack_i8(const float* __restrict__ in, char* __restrict__ out, int n4) {
  int i = blockIdx.x * blockDim.x + threadIdx.x;
  if (i >= n4) return;
  float4 v = ((const float4*)in)[i];
  union { char c[4]; int w; } o;
  o.c[0] = sign8(v.x); o.c[1] = sign8(v.y); o.c[2] = sign8(v.z); o.c[3] = sign8(v.w);
  ((int*)out)[i] = o.w;
}

// w3 [1000,4096] fp32 -> [1024,4096] bf16, rows >= 1000 zero-filled
__global__ void w3_cast(const float* __restrict__ in, __hip_bfloat16* __restrict__ out, int rows_valid) {
  int i = blockIdx.x * blockDim.x + threadIdx.x;   // over 1024*4096/4
  int idx = i * 4;
  int row = idx >> 12;                              // 4096 cols
  union { ushort4 u; __hip_bfloat16 h[4]; } o;
  if (row < rows_valid) {
    float4 v = *(const float4*)(in + idx);
    o.h[0] = __float2bfloat16(v.x);
    o.h[1] = __float2bfloat16(v.y);
    o.h[2] = __float2bfloat16(v.z);
    o.h[3] = __float2bfloat16(v.w);
  } else {
    o.h[0] = o.h[1] = o.h[2] = o.h[3] = __float2bfloat16(0.f);
  }
  ((ushort4*)out)[i] = o.u;
}

// ---------------------------------------------------------------------------
// Ternary i8 GEMM: C = A @ B^T (+bias), A [M,K] i8 row-major, B [N,K] i8.
// 128x128 tile, IBK=64, mfma_i32_16x16x64_i8, 4 waves x 4x4 16x16 tiles.
// LDS layout: [kchunk c=0..3][row 0..127] x 16B slots  (addr = c*2048 + row*16).
//   - staging: thread t loads global (row=t&127, kbytes [sc*16,sc*16+16)) -> LDS t*16
//     (global source 16B-contiguous; LDS dest forced wave-uniform+lane*16 -> matches)
//   - frag read: lane (c=lane>>4, r=lane&15): addr = c*2048 + (rbase+r)*16.
//     16 consecutive lanes sweep all 32 banks exactly 2x -> conflict-free (m136).
// EPI=0: Ci8[m][n] = sign(acc+bias[n]) as i8.  EPI=1: Cbf[m][n] = bf16(sign(...)).
// ---------------------------------------------------------------------------
template <int EPI>
__global__ __launch_bounds__(256)
void gemm_i8(const char* __restrict__ A,
             const char* __restrict__ B,
             const float* __restrict__ bias,
             char* __restrict__ Ci8,
             __hip_bfloat16* __restrict__ Cbf,
             int K, int ldc)
{
  __shared__ char As[4 * 128 * 16];   // 8 KB
  __shared__ char Bs[4 * 128 * 16];   // 8 KB

  const int tid  = threadIdx.x;
  const int lane = tid & 63;
  const int wid  = tid >> 6;
  const int wy   = wid >> 1;
  const int wx   = wid & 1;

  const int m0 = blockIdx.y * BM;
  const int n0 = blockIdx.x * BN;

  // staging source: row = tid&127, k-chunk sc = tid>>7 (and sc+2 for 2nd stage)
  const int srow = tid & 127;
  const int sc   = tid >> 7;
  const char* Ag = A + (size_t)(m0 + srow) * K + sc * 16;
  const char* Bg = B + (size_t)(n0 + srow) * K + sc * 16;
  char* Asl  = As + tid * 16;          // slot (c=sc,   row=srow)
  char* Asl2 = As + tid * 16 + 4096;   // slot (c=sc+2, row=srow)
  char* Bsl  = Bs + tid * 16;
  char* Bsl2 = Bs + tid * 16 + 4096;

  i32x4 acc[4][4];
#pragma unroll
  for (int i = 0; i < 4; ++i)
#pragma unroll
    for (int j = 0; j < 4; ++j)
      acc[i][j] = (i32x4){0, 0, 0, 0};

  const int fc = (lane >> 4) * 2048;   // k-chunk byte base in LDS
  const int fr = lane & 15;            // row within 16-tile

  for (int k0 = 0; k0 < K; k0 += IBK) {
    async_copy16(Ag + k0,      Asl);
    async_copy16(Ag + k0 + 32, Asl2);
    async_copy16(Bg + k0,      Bsl);
    async_copy16(Bg + k0 + 32, Bsl2);
    __syncthreads();   // drains vmcnt -> staged data visible

    i32x4 a[4], b[4];
#pragma unroll
    for (int i = 0; i < 4; ++i)
      a[i] = *(const i32x4*)(As + fc + (wy * 64 + i * 16 + fr) * 16);   // ds_read_b128, conflict-free
#pragma unroll
    for (int j = 0; j < 4; ++j)
      b[j] = *(const i32x4*)(Bs + fc + (wx * 64 + j * 16 + fr) * 16);

#pragma unroll
    for (int i = 0; i < 4; ++i)
#pragma unroll
      for (int j = 0; j < 4; ++j)
        acc[i][j] = __builtin_amdgcn_mfma_i32_16x16x64_i8(a[i], b[j], acc[i][j], 0, 0, 0);
    __syncthreads();
  }

  // C/D layout (shape-determined, dtype-independent): col=lane&15, row=(lane>>4)*4+reg
  const int ccol = lane & 15;
  const int crow = (lane >> 4) * 4;
#pragma unroll
  for (int i = 0; i < 4; ++i) {
    const int m = m0 + wy * 64 + i * 16 + crow;
#pragma unroll
    for (int j = 0; j < 4; ++j) {
      const int n = n0 + wx * 64 + j * 16 + ccol;
      const float bv = bias[n];
#pragma unroll
      for (int r = 0; r < 4; ++r) {
        float v = (float)acc[i][j][r] + bv;
        if (EPI == 0) Ci8[(size_t)(m + r) * ldc + n] = sign8(v);
        else          Cbf[(size_t)(m + r) * ldc + n] = __float2bfloat16(signf(v));
      }
    }
  }
}

// ---------------------------------------------------------------------------
// bf16 GEMM (m97 structure) for layer 3: C = A @ B^T + bias, fp32 out,
// guarded n < nvalid. A [M,K] bf16, B [N,K] bf16.
// ---------------------------------------------------------------------------
__global__ __launch_bounds__(256)
void gemm_bt(const __hip_bfloat16* __restrict__ A,
             const __hip_bfloat16* __restrict__ B,
             const float* __restrict__ bias,
             float* __restrict__ Cf,
             int K, int ldc, int nvalid)
{
  __shared__ __hip_bfloat16 As[BM * BK];
  __shared__ __hip_bfloat16 Bs[BN * BK];

  const int tid  = threadIdx.x;
  const int lane = tid & 63;
  const int wid  = tid >> 6;
  const int wy   = wid >> 1;
  const int wx   = wid & 1;

  const int m0 = blockIdx.y * BM;
  const int n0 = blockIdx.x * BN;

  const int srow = tid >> 2;
  const int scol = (tid & 3) * 8;
  const __hip_bfloat16* Ag = A + (size_t)(m0 + srow) * K + scol;
  const __hip_bfloat16* Bg = B + (size_t)(n0 + srow) * K + scol;
  __hip_bfloat16* Asl  = As + tid * 8;
  __hip_bfloat16* Asl2 = As + (256 + tid) * 8;
  __hip_bfloat16* Bsl  = Bs + tid * 8;
  __hip_bfloat16* Bsl2 = Bs + (256 + tid) * 8;
  const size_t rowskip = (size_t)64 * K;

  f32x4 acc[4][4];
#pragma unroll
  for (int i = 0; i < 4; ++i)
#pragma unroll
    for (int j = 0; j < 4; ++j)
      acc[i][j] = (f32x4){0.f, 0.f, 0.f, 0.f};

  const int fr = lane & 15;
  const int fk = (lane >> 4) * 8;

  for (int k0 = 0; k0 < K; k0 += BK) {
    async_copy16(Ag + k0, Asl);
    async_copy16(Ag + rowskip + k0, Asl2);
    async_copy16(Bg + k0, Bsl);
    async_copy16(Bg + rowskip + k0, Bsl2);
    __syncthreads();

    bf16x8 a[4], b[4];
#pragma unroll
    for (int i = 0; i < 4; ++i)
      a[i] = *(const bf16x8*)(As + (wy * 64 + i * 16 + fr) * BK + fk);
#pragma unroll
    for (int j = 0; j < 4; ++j)
      b[j] = *(const bf16x8*)(Bs + (wx * 64 + j * 16 + fr) * BK + fk);

#pragma unroll
    for (int i = 0; i < 4; ++i)
#pragma unroll
      for (int j = 0; j < 4; ++j)
        acc[i][j] = __builtin_amdgcn_mfma_f32_16x16x32_bf16(a[i], b[j], acc[i][j], 0, 0, 0);
    __syncthreads();
  }

  const int ccol = lane & 15;
  const int crow = (lane >> 4) * 4;
#pragma unroll
  for (int i = 0; i < 4; ++i) {
    const int m = m0 + wy * 64 + i * 16 + crow;
#pragma unroll
    for (int j = 0; j < 4; ++j) {
      const int n = n0 + wx * 64 + j * 16 + ccol;
      if (n >= nvalid) continue;
      const float bv = bias[n];
#pragma unroll
      for (int r = 0; r < 4; ++r) {
        Cf[(size_t)(m + r) * ldc + n] = acc[i][j][r] + bv;
      }
    }
  }
}

extern "C" void kernel_launch(void* const* d_in, const int* in_sizes, int n_in,
                              void* d_out, int out_size, void* d_ws, size_t ws_size,
                              hipStream_t stream) {
  const float* x  = (const float*)d_in[0];   // [8192,4096]
  const float* w1 = (const float*)d_in[1];   // [4096,4096]
  const float* b1 = (const float*)d_in[2];   // [4096]
  const float* w2 = (const float*)d_in[3];   // [4096,4096]
  const float* b2 = (const float*)d_in[4];   // [4096]
  const float* w3 = (const float*)d_in[5];   // [1000,4096]
  const float* b3 = (const float*)d_in[6];   // [1000]

  const int Mb = 8192, H = 4096, C = 1000, Cpad = 1024;

  // workspace layout (168 MB used):
  //   [0,32M)     sx  = sign(x) i8
  //   [32M,48M)   sw1 i8
  //   [48M,64M)   sw2 i8
  //   [64M,72M)   w3b (1024x4096 bf16, padded)
  //   [72M,104M)  a1  i8
  //   [104M,168M) a2  bf16
  char* ws = (char*)d_ws;
  char*           sx  = ws;
  char*           sw1 = ws + (size_t)33554432;
  char*           sw2 = ws + (size_t)50331648;
  __hip_bfloat16* w3b = (__hip_bfloat16*)(ws + (size_t)67108864);
  char*           a1  = ws + (size_t)75497472;
  __hip_bfloat16* a2  = (__hip_bfloat16*)(ws + (size_t)109051904);

  sign_pack_i8<<<(Mb * H / 4 + 255) / 256, 256, 0, stream>>>(x,  sx,  Mb * H / 4);
  sign_pack_i8<<<(H * H / 4 + 255) / 256, 256, 0, stream>>>(w1, sw1, H * H / 4);
  sign_pack_i8<<<(H * H / 4 + 255) / 256, 256, 0, stream>>>(w2, sw2, H * H / 4);
  w3_cast<<<(Cpad * H / 4 + 255) / 256, 256, 0, stream>>>(w3, w3b, C);

  dim3 blk(256);
  // layer 1: a1 = sign(sign(x) @ sign(w1)^T + b1)   [exact, i8/i32]
  gemm_i8<0><<<dim3(H / BN, Mb / BM), blk, 0, stream>>>(sx, sw1, b1, a1, nullptr, H, H);
  // layer 2: a2 = sign(a1 @ sign(w2)^T + b2)        [exact, a1 ternary]
  gemm_i8<1><<<dim3(H / BN, Mb / BM), blk, 0, stream>>>(a1, sw2, b2, nullptr, a2, H, H);
  // layer 3: out = a2 @ w3^T + b3                    [bf16-rounded w3]
  gemm_bt<<<dim3(Cpad / BN, Mb / BM), blk, 0, stream>>>(a2, w3b, b3, (float*)d_out, H, C, C);
}

// Round 3
// 745.663 us; speedup vs baseline: 1.4574x; 1.2569x over previous
//
#include <hip/hip_runtime.h>
#include <hip/hip_bf16.h>

// SimpleBNN: out = sign(sign(sign(x)@sign(w1)T + b1) @ sign(w2)T + b2) @ w3T + b3
// Layers 1-2: exact ternary GEMM via i8 MFMA (i32 accum, |sums| <= 4096 -> exact).
// Layer 3: bf16 MFMA, w3 rounded to bf16 (error ~1.6e-2 << 6.5e-2 threshold).
//
// LDS tiles use an XOR-swizzled layout (16B granules):
//   slot s in [0,512) <-> (row = s>>2, chunk c = (s&3) ^ ((row>>1)&3))
// - staging (global_load_lds dest forced to tid*16): 4 consecutive lanes fetch a
//   permutation of 4 contiguous 16B chunks of one row -> 16 x 64B lines per wave
//   (coalesced, vs 64 scattered lines in the round-2 [chunk][row] layout)
// - fragment reads: slot = row*4 + (kc ^ ((row>>1)&3)); per 16-lane phase each
//   4-bank group is hit exactly 2x -> 2-way aliasing = free (m136)

typedef __attribute__((ext_vector_type(8))) short bf16x8;
typedef __attribute__((ext_vector_type(4))) float f32x4;
typedef __attribute__((ext_vector_type(4))) int   i32x4;

#define BM 128
#define BN 128

__device__ __forceinline__ void async_copy16(const void* g, void* l) {
  __builtin_amdgcn_global_load_lds(
      (const __attribute__((address_space(1))) void*)g,
      (__attribute__((address_space(3))) void*)l,
      16, 0, 0);
}

__device__ __forceinline__ float signf(float v) {
  return (v > 0.f) ? 1.f : ((v < 0.f) ? -1.f : 0.f);
}
__device__ __forceinline__ char sign8(float v) {
  return (v > 0.f) ? (char)1 : ((v < 0.f) ? (char)-1 : (char)0);
}

// fp32 -> i8 sign cast, 4 elems/thread (4B coalesced stores)
__global__ void sign_pack_i8(const float* __restrict__ in, char* __restrict__ out, int n4) {
  int i = blockIdx.x * blockDim.x + threadIdx.x;
  if (i >= n4) return;
  float4 v = ((const float4*)in)[i];
  union { char c[4]; int w; } o;
  o.c[0] = sign8(v.x); o.c[1] = sign8(v.y); o.c[2] = sign8(v.z); o.c[3] = sign8(v.w);
  ((int*)out)[i] = o.w;
}

// w3 [1000,4096] fp32 -> [1024,4096] bf16, rows >= 1000 zero-filled
__global__ void w3_cast(const float* __restrict__ in, __hip_bfloat16* __restrict__ out, int rows_valid) {
  int i = blockIdx.x * blockDim.x + threadIdx.x;
  int idx = i * 4;
  int row = idx >> 12;
  union { ushort4 u; __hip_bfloat16 h[4]; } o;
  if (row < rows_valid) {
    float4 v = *(const float4*)(in + idx);
    o.h[0] = __float2bfloat16(v.x);
    o.h[1] = __float2bfloat16(v.y);
    o.h[2] = __float2bfloat16(v.z);
    o.h[3] = __float2bfloat16(v.w);
  } else {
    o.h[0] = o.h[1] = o.h[2] = o.h[3] = __float2bfloat16(0.f);
  }
  ((ushort4*)out)[i] = o.u;
}

// ---------------------------------------------------------------------------
// Ternary i8 GEMM: C = A @ B^T (+bias). 128x128 tile, IBK=64 (one 64B row of
// k-bytes per tile-row), mfma_i32_16x16x64_i8, 4 waves x 4x4 16x16 tiles.
// EPI=0: Ci8[m][n] = sign(acc+bias[n]).  EPI=1: Cbf[m][n] = bf16(sign(...)).
// ---------------------------------------------------------------------------
template <int EPI>
__global__ __launch_bounds__(256)
void gemm_i8(const char* __restrict__ A,
             const char* __restrict__ B,
             const float* __restrict__ bias,
             char* __restrict__ Ci8,
             __hip_bfloat16* __restrict__ Cbf,
             int K, int ldc)
{
  __shared__ char As[128 * 64];   // 8 KB, swizzled 16B granules
  __shared__ char Bs[128 * 64];   // 8 KB

  const int tid  = threadIdx.x;
  const int lane = tid & 63;
  const int wid  = tid >> 6;
  const int wy   = wid >> 1;
  const int wx   = wid & 1;

  const int m0 = blockIdx.y * BM;
  const int n0 = blockIdx.x * BN;

  // staging: thread t fills slots t (rows 0..63) and t+256 (rows 64..127).
  // slot s: row = s>>2, global chunk c = (s&3) ^ ((row>>1)&3)
  const int r1 = tid >> 2;
  const int r2 = r1 + 64;
  const int c1 = (tid & 3) ^ ((r1 >> 1) & 3);
  const int c2 = (tid & 3) ^ ((r2 >> 1) & 3);
  const char* Ag1 = A + (size_t)(m0 + r1) * K + c1 * 16;
  const char* Ag2 = A + (size_t)(m0 + r2) * K + c2 * 16;
  const char* Bg1 = B + (size_t)(n0 + r1) * K + c1 * 16;
  const char* Bg2 = B + (size_t)(n0 + r2) * K + c2 * 16;
  char* Asl1 = As + tid * 16;
  char* Asl2 = As + (tid + 256) * 16;
  char* Bsl1 = Bs + tid * 16;
  char* Bsl2 = Bs + (tid + 256) * 16;

  i32x4 acc[4][4];
#pragma unroll
  for (int i = 0; i < 4; ++i)
#pragma unroll
    for (int j = 0; j < 4; ++j)
      acc[i][j] = (i32x4){0, 0, 0, 0};

  const int fr  = lane & 15;                      // row within 16-tile
  const int kc  = lane >> 4;                      // k-chunk 0..3
  const int swz = (kc ^ ((fr >> 1) & 3)) * 16;    // swizzled chunk byte offset

  for (int k0 = 0; k0 < K; k0 += 64) {
    async_copy16(Ag1 + k0, Asl1);
    async_copy16(Ag2 + k0, Asl2);
    async_copy16(Bg1 + k0, Bsl1);
    async_copy16(Bg2 + k0, Bsl2);
    __syncthreads();   // drains vmcnt -> staged data visible

    i32x4 a[4], b[4];
#pragma unroll
    for (int i = 0; i < 4; ++i)
      a[i] = *(const i32x4*)(As + (wy * 64 + i * 16 + fr) * 64 + swz);  // ds_read_b128
#pragma unroll
    for (int j = 0; j < 4; ++j)
      b[j] = *(const i32x4*)(Bs + (wx * 64 + j * 16 + fr) * 64 + swz);

#pragma unroll
    for (int i = 0; i < 4; ++i)
#pragma unroll
      for (int j = 0; j < 4; ++j)
        acc[i][j] = __builtin_amdgcn_mfma_i32_16x16x64_i8(a[i], b[j], acc[i][j], 0, 0, 0);
    __syncthreads();
  }

  // C/D layout (shape-determined): col=lane&15, row=(lane>>4)*4+reg
  const int ccol = lane & 15;
  const int crow = (lane >> 4) * 4;
#pragma unroll
  for (int i = 0; i < 4; ++i) {
    const int m = m0 + wy * 64 + i * 16 + crow;
#pragma unroll
    for (int j = 0; j < 4; ++j) {
      const int n = n0 + wx * 64 + j * 16 + ccol;
      const float bv = bias[n];
#pragma unroll
      for (int r = 0; r < 4; ++r) {
        float v = (float)acc[i][j][r] + bv;
        if (EPI == 0) Ci8[(size_t)(m + r) * ldc + n] = sign8(v);
        else          Cbf[(size_t)(m + r) * ldc + n] = __float2bfloat16(signf(v));
      }
    }
  }
}

// ---------------------------------------------------------------------------
// bf16 GEMM for layer 3: C = A @ B^T + bias, fp32 out, guarded n < nvalid.
// Same swizzled-layout structure; BK=32 bf16 = 64B rows, chunk = 8 bf16.
// ---------------------------------------------------------------------------
__global__ __launch_bounds__(256)
void gemm_bt(const __hip_bfloat16* __restrict__ A,
             const __hip_bfloat16* __restrict__ B,
             const float* __restrict__ bias,
             float* __restrict__ Cf,
             int K, int ldc, int nvalid)
{
  __shared__ char As[128 * 64];   // 8 KB (bf16 tile stored as swizzled 16B granules)
  __shared__ char Bs[128 * 64];

  const int tid  = threadIdx.x;
  const int lane = tid & 63;
  const int wid  = tid >> 6;
  const int wy   = wid >> 1;
  const int wx   = wid & 1;

  const int m0 = blockIdx.y * BM;
  const int n0 = blockIdx.x * BN;

  const int r1 = tid >> 2;
  const int r2 = r1 + 64;
  const int c1 = (tid & 3) ^ ((r1 >> 1) & 3);
  const int c2 = (tid & 3) ^ ((r2 >> 1) & 3);
  const __hip_bfloat16* Ag1 = A + (size_t)(m0 + r1) * K + c1 * 8;
  const __hip_bfloat16* Ag2 = A + (size_t)(m0 + r2) * K + c2 * 8;
  const __hip_bfloat16* Bg1 = B + (size_t)(n0 + r1) * K + c1 * 8;
  const __hip_bfloat16* Bg2 = B + (size_t)(n0 + r2) * K + c2 * 8;
  char* Asl1 = As + tid * 16;
  char* Asl2 = As + (tid + 256) * 16;
  char* Bsl1 = Bs + tid * 16;
  char* Bsl2 = Bs + (tid + 256) * 16;

  f32x4 acc[4][4];
#pragma unroll
  for (int i = 0; i < 4; ++i)
#pragma unroll
    for (int j = 0; j < 4; ++j)
      acc[i][j] = (f32x4){0.f, 0.f, 0.f, 0.f};

  const int fr  = lane & 15;
  const int kc  = lane >> 4;
  const int swz = (kc ^ ((fr >> 1) & 3)) * 16;

  for (int k0 = 0; k0 < K; k0 += 32) {   // 32 bf16 = 64 bytes per row per iter
    async_copy16(Ag1 + k0, Asl1);
    async_copy16(Ag2 + k0, Asl2);
    async_copy16(Bg1 + k0, Bsl1);
    async_copy16(Bg2 + k0, Bsl2);
    __syncthreads();

    bf16x8 a[4], b[4];
#pragma unroll
    for (int i = 0; i < 4; ++i)
      a[i] = *(const bf16x8*)(As + (wy * 64 + i * 16 + fr) * 64 + swz);
#pragma unroll
    for (int j = 0; j < 4; ++j)
      b[j] = *(const bf16x8*)(Bs + (wx * 64 + j * 16 + fr) * 64 + swz);

#pragma unroll
    for (int i = 0; i < 4; ++i)
#pragma unroll
      for (int j = 0; j < 4; ++j)
        acc[i][j] = __builtin_amdgcn_mfma_f32_16x16x32_bf16(a[i], b[j], acc[i][j], 0, 0, 0);
    __syncthreads();
  }

  const int ccol = lane & 15;
  const int crow = (lane >> 4) * 4;
#pragma unroll
  for (int i = 0; i < 4; ++i) {
    const int m = m0 + wy * 64 + i * 16 + crow;
#pragma unroll
    for (int j = 0; j < 4; ++j) {
      const int n = n0 + wx * 64 + j * 16 + ccol;
      if (n >= nvalid) continue;
      const float bv = bias[n];
#pragma unroll
      for (int r = 0; r < 4; ++r) {
        Cf[(size_t)(m + r) * ldc + n] = acc[i][j][r] + bv;
      }
    }
  }
}

extern "C" void kernel_launch(void* const* d_in, const int* in_sizes, int n_in,
                              void* d_out, int out_size, void* d_ws, size_t ws_size,
                              hipStream_t stream) {
  const float* x  = (const float*)d_in[0];   // [8192,4096]
  const float* w1 = (const float*)d_in[1];   // [4096,4096]
  const float* b1 = (const float*)d_in[2];   // [4096]
  const float* w2 = (const float*)d_in[3];   // [4096,4096]
  const float* b2 = (const float*)d_in[4];   // [4096]
  const float* w3 = (const float*)d_in[5];   // [1000,4096]
  const float* b3 = (const float*)d_in[6];   // [1000]

  const int Mb = 8192, H = 4096, C = 1000, Cpad = 1024;

  // workspace layout:
  //   [0,32M)     sx  = sign(x) i8
  //   [32M,48M)   sw1 i8
  //   [48M,64M)   sw2 i8
  //   [64M,72M)   w3b (1024x4096 bf16, padded)
  //   [72M,104M)  a1  i8
  //   [104M,168M) a2  bf16
  char* ws = (char*)d_ws;
  char*           sx  = ws;
  char*           sw1 = ws + (size_t)33554432;
  char*           sw2 = ws + (size_t)50331648;
  __hip_bfloat16* w3b = (__hip_bfloat16*)(ws + (size_t)67108864);
  char*           a1  = ws + (size_t)75497472;
  __hip_bfloat16* a2  = (__hip_bfloat16*)(ws + (size_t)109051904);

  sign_pack_i8<<<(Mb * H / 4 + 255) / 256, 256, 0, stream>>>(x,  sx,  Mb * H / 4);
  sign_pack_i8<<<(H * H / 4 + 255) / 256, 256, 0, stream>>>(w1, sw1, H * H / 4);
  sign_pack_i8<<<(H * H / 4 + 255) / 256, 256, 0, stream>>>(w2, sw2, H * H / 4);
  w3_cast<<<(Cpad * H / 4 + 255) / 256, 256, 0, stream>>>(w3, w3b, C);

  dim3 blk(256);
  // layer 1: a1 = sign(sign(x) @ sign(w1)^T + b1)   [exact, i8/i32]
  gemm_i8<0><<<dim3(H / BN, Mb / BM), blk, 0, stream>>>(sx, sw1, b1, a1, nullptr, H, H);
  // layer 2: a2 = sign(a1 @ sign(w2)^T + b2)        [exact, a1 ternary]
  gemm_i8<1><<<dim3(H / BN, Mb / BM), blk, 0, stream>>>(a1, sw2, b2, nullptr, a2, H, H);
  // layer 3: out = a2 @ w3^T + b3                    [bf16-rounded w3]
  gemm_bt<<<dim3(Cpad / BN, Mb / BM), blk, 0, stream>>>(a2, w3b, b3, (float*)d_out, H, C, C);
}

// Round 4
// 596.442 us; speedup vs baseline: 1.8220x; 1.2502x over previous
//
#include <hip/hip_runtime.h>
#include <hip/hip_bf16.h>

// SimpleBNN: out = sign(sign(sign(x)@sign(w1)T + b1) @ sign(w2)T + b2) @ w3T + b3
// Layers 1-2: exact ternary GEMM via MX-fp4 MFMA (K=128/inst, scale=1.0):
//   fp4 e2m1 represents {-1,0,+1} exactly; products +-1, |sums|<=4096 << 2^24
//   with fp32 accumulation -> bit-exact vs the numpy reference.
// Layer 3: bf16 MFMA, w3 rounded to bf16 (error ~1.6e-2 << 6.5e-2 threshold).
//
// LDS tiles use the round-3 XOR-swizzled layout (16B granules):
//   slot s in [0,512) <-> (row = s>>2, chunk c = (s&3) ^ ((row>>1)&3))
// staging stays coalesced (16 x 64B lines/wave) and fragment ds_read_b128s are
// conflict-free (2-way aliasing = free, m136). Byte addressing is IDENTICAL to
// the verified i8 kernel; only the element interpretation (fp4 pairs) changes.
// Any consistent within-row k-permutation (nibble order, granule order) applied
// to both A and B cancels in A@B^T, so pack-order conventions are risk-free.

typedef __attribute__((ext_vector_type(8))) short bf16x8;
typedef __attribute__((ext_vector_type(4))) float f32x4;
typedef __attribute__((ext_vector_type(4))) int   i32x4;
typedef __attribute__((ext_vector_type(8))) int   i32x8;

#define BM 128
#define BN 128

__device__ __forceinline__ void async_copy16(const void* g, void* l) {
  __builtin_amdgcn_global_load_lds(
      (const __attribute__((address_space(1))) void*)g,
      (__attribute__((address_space(3))) void*)l,
      16, 0, 0);
}

__device__ __forceinline__ float signf(float v) {
  return (v > 0.f) ? 1.f : ((v < 0.f) ? -1.f : 0.f);
}
__device__ __forceinline__ char sign8(float v) {
  return (v > 0.f) ? (char)1 : ((v < 0.f) ? (char)-1 : (char)0);
}
// fp4 e2m1 nibble for sign: +1 -> 0x2, -1 -> 0xA, 0 -> 0x0
__device__ __forceinline__ unsigned nib4(float v) {
  return (v > 0.f) ? 0x2u : ((v < 0.f) ? 0xAu : 0x0u);
}

// fp32 -> packed fp4 sign, 8 elems/thread (4B coalesced stores)
__global__ void sign_pack_fp4(const float* __restrict__ in, unsigned* __restrict__ out, int n8) {
  int i = blockIdx.x * blockDim.x + threadIdx.x;
  if (i >= n8) return;
  const float4* p = (const float4*)in + (size_t)i * 2;
  float4 v0 = p[0], v1 = p[1];
  unsigned b0 = nib4(v0.x) | (nib4(v0.y) << 4);
  unsigned b1 = nib4(v0.z) | (nib4(v0.w) << 4);
  unsigned b2 = nib4(v1.x) | (nib4(v1.y) << 4);
  unsigned b3 = nib4(v1.z) | (nib4(v1.w) << 4);
  out[i] = b0 | (b1 << 8) | (b2 << 16) | (b3 << 24);
}

// i8 {-1,0,1} -> packed fp4, 8 elems/thread
__global__ void repack_i8_fp4(const char* __restrict__ in, unsigned* __restrict__ out, int n8) {
  int i = blockIdx.x * blockDim.x + threadIdx.x;
  if (i >= n8) return;
  int2 w = ((const int2*)in)[i];
  union { int2 d; char c[8]; } u; u.d = w;
  unsigned r = 0;
#pragma unroll
  for (int j = 0; j < 8; ++j) {
    char v = u.c[j];
    unsigned nb = (v == 1) ? 0x2u : ((v == (char)-1) ? 0xAu : 0x0u);
    r |= nb << (4 * j);
  }
  out[i] = r;
}

// w3 [1000,4096] fp32 -> [1024,4096] bf16, rows >= 1000 zero-filled
__global__ void w3_cast(const float* __restrict__ in, __hip_bfloat16* __restrict__ out, int rows_valid) {
  int i = blockIdx.x * blockDim.x + threadIdx.x;
  int idx = i * 4;
  int row = idx >> 12;
  union { ushort4 u; __hip_bfloat16 h[4]; } o;
  if (row < rows_valid) {
    float4 v = *(const float4*)(in + idx);
    o.h[0] = __float2bfloat16(v.x);
    o.h[1] = __float2bfloat16(v.y);
    o.h[2] = __float2bfloat16(v.z);
    o.h[3] = __float2bfloat16(v.w);
  } else {
    o.h[0] = o.h[1] = o.h[2] = o.h[3] = __float2bfloat16(0.f);
  }
  ((ushort4*)out)[i] = o.u;
}

// ---------------------------------------------------------------------------
// Ternary MX-fp4 GEMM: C = A @ B^T (+bias). A [M,Kb] / B [N,Kb] packed fp4
// (Kb = K/2 bytes). 128x128 tile, one barrier-pair covers K=128 (64B/row),
// mfma_scale_f32_16x16x128_f8f6f4 (cbsz=blgp=4 -> fp4, scales 0x7F = 2^0).
// 4 waves x 4x4 16x16 tiles. Fragment: lane holds 16B = 32 fp4 of k-quadrant
// (lane>>4)*32, rows fr=lane&15 -- byte-identical addressing to the i8 kernel.
// EPI=0: Ci8[m][n] = sign(acc+bias[n]).  EPI=1: Cbf[m][n] = bf16(sign(...)).
// ---------------------------------------------------------------------------
template <int EPI>
__global__ __launch_bounds__(256)
void gemm_fp4(const unsigned char* __restrict__ A,
              const unsigned char* __restrict__ B,
              const float* __restrict__ bias,
              char* __restrict__ Ci8,
              __hip_bfloat16* __restrict__ Cbf,
              int Kb, int ldc)
{
  __shared__ unsigned char As[128 * 64];   // 8 KB, swizzled 16B granules
  __shared__ unsigned char Bs[128 * 64];   // 8 KB

  const int tid  = threadIdx.x;
  const int lane = tid & 63;
  const int wid  = tid >> 6;
  const int wy   = wid >> 1;
  const int wx   = wid & 1;

  const int m0 = blockIdx.y * BM;
  const int n0 = blockIdx.x * BN;

  // staging: thread t fills slots t (rows 0..63) and t+256 (rows 64..127)
  const int r1 = tid >> 2;
  const int r2 = r1 + 64;
  const int c1 = (tid & 3) ^ ((r1 >> 1) & 3);
  const int c2 = (tid & 3) ^ ((r2 >> 1) & 3);
  const unsigned char* Ag1 = A + (size_t)(m0 + r1) * Kb + c1 * 16;
  const unsigned char* Ag2 = A + (size_t)(m0 + r2) * Kb + c2 * 16;
  const unsigned char* Bg1 = B + (size_t)(n0 + r1) * Kb + c1 * 16;
  const unsigned char* Bg2 = B + (size_t)(n0 + r2) * Kb + c2 * 16;
  unsigned char* Asl1 = As + tid * 16;
  unsigned char* Asl2 = As + (tid + 256) * 16;
  unsigned char* Bsl1 = Bs + tid * 16;
  unsigned char* Bsl2 = Bs + (tid + 256) * 16;

  f32x4 acc[4][4];
#pragma unroll
  for (int i = 0; i < 4; ++i)
#pragma unroll
    for (int j = 0; j < 4; ++j)
      acc[i][j] = (f32x4){0.f, 0.f, 0.f, 0.f};

  const int fr  = lane & 15;                      // row within 16-tile
  const int kc  = lane >> 4;                      // k-quadrant 0..3
  const int swz = (kc ^ ((fr >> 1) & 3)) * 16;    // swizzled granule byte offset

  for (int k0 = 0; k0 < Kb; k0 += 64) {           // 64 bytes = 128 fp4 per iter
    async_copy16(Ag1 + k0, Asl1);
    async_copy16(Ag2 + k0, Asl2);
    async_copy16(Bg1 + k0, Bsl1);
    async_copy16(Bg2 + k0, Bsl2);
    __syncthreads();   // drains vmcnt -> staged data visible

    i32x8 a[4], b[4];
#pragma unroll
    for (int i = 0; i < 4; ++i) {
      i32x4 t = *(const i32x4*)(As + (wy * 64 + i * 16 + fr) * 64 + swz);
      a[i] = (i32x8){t[0], t[1], t[2], t[3], 0, 0, 0, 0};   // fp4 reads regs 0..3 only
    }
#pragma unroll
    for (int j = 0; j < 4; ++j) {
      i32x4 t = *(const i32x4*)(Bs + (wx * 64 + j * 16 + fr) * 64 + swz);
      b[j] = (i32x8){t[0], t[1], t[2], t[3], 0, 0, 0, 0};
    }

#pragma unroll
    for (int i = 0; i < 4; ++i)
#pragma unroll
      for (int j = 0; j < 4; ++j)
        acc[i][j] = __builtin_amdgcn_mfma_scale_f32_16x16x128_f8f6f4(
            a[i], b[j], acc[i][j],
            4, 4,                 // cbsz=fp4(e2m1), blgp=fp4(e2m1)
            0, 0x7f7f7f7f,        // scale_a opsel, scale_a bytes = 127 -> 2^0
            0, 0x7f7f7f7f);       // scale_b
    __syncthreads();
  }

  // C/D layout (shape-determined, m121-m128): col=lane&15, row=(lane>>4)*4+reg
  const int ccol = lane & 15;
  const int crow = (lane >> 4) * 4;
#pragma unroll
  for (int i = 0; i < 4; ++i) {
    const int m = m0 + wy * 64 + i * 16 + crow;
#pragma unroll
    for (int j = 0; j < 4; ++j) {
      const int n = n0 + wx * 64 + j * 16 + ccol;
      const float bv = bias[n];
#pragma unroll
      for (int r = 0; r < 4; ++r) {
        float v = acc[i][j][r] + bv;
        if (EPI == 0) Ci8[(size_t)(m + r) * ldc + n] = sign8(v);
        else          Cbf[(size_t)(m + r) * ldc + n] = __float2bfloat16(signf(v));
      }
    }
  }
}

// ---------------------------------------------------------------------------
// bf16 GEMM for layer 3 (unchanged from round 3): C = A @ B^T + bias, fp32 out,
// guarded n < nvalid. Swizzled layout, BK=32 bf16 = 64B rows.
// ---------------------------------------------------------------------------
__global__ __launch_bounds__(256)
void gemm_bt(const __hip_bfloat16* __restrict__ A,
             const __hip_bfloat16* __restrict__ B,
             const float* __restrict__ bias,
             float* __restrict__ Cf,
             int K, int ldc, int nvalid)
{
  __shared__ char As[128 * 64];
  __shared__ char Bs[128 * 64];

  const int tid  = threadIdx.x;
  const int lane = tid & 63;
  const int wid  = tid >> 6;
  const int wy   = wid >> 1;
  const int wx   = wid & 1;

  const int m0 = blockIdx.y * BM;
  const int n0 = blockIdx.x * BN;

  const int r1 = tid >> 2;
  const int r2 = r1 + 64;
  const int c1 = (tid & 3) ^ ((r1 >> 1) & 3);
  const int c2 = (tid & 3) ^ ((r2 >> 1) & 3);
  const __hip_bfloat16* Ag1 = A + (size_t)(m0 + r1) * K + c1 * 8;
  const __hip_bfloat16* Ag2 = A + (size_t)(m0 + r2) * K + c2 * 8;
  const __hip_bfloat16* Bg1 = B + (size_t)(n0 + r1) * K + c1 * 8;
  const __hip_bfloat16* Bg2 = B + (size_t)(n0 + r2) * K + c2 * 8;
  char* Asl1 = As + tid * 16;
  char* Asl2 = As + (tid + 256) * 16;
  char* Bsl1 = Bs + tid * 16;
  char* Bsl2 = Bs + (tid + 256) * 16;

  f32x4 acc[4][4];
#pragma unroll
  for (int i = 0; i < 4; ++i)
#pragma unroll
    for (int j = 0; j < 4; ++j)
      acc[i][j] = (f32x4){0.f, 0.f, 0.f, 0.f};

  const int fr  = lane & 15;
  const int kc  = lane >> 4;
  const int swz = (kc ^ ((fr >> 1) & 3)) * 16;

  for (int k0 = 0; k0 < K; k0 += 32) {
    async_copy16(Ag1 + k0, Asl1);
    async_copy16(Ag2 + k0, Asl2);
    async_copy16(Bg1 + k0, Bsl1);
    async_copy16(Bg2 + k0, Bsl2);
    __syncthreads();

    bf16x8 a[4], b[4];
#pragma unroll
    for (int i = 0; i < 4; ++i)
      a[i] = *(const bf16x8*)(As + (wy * 64 + i * 16 + fr) * 64 + swz);
#pragma unroll
    for (int j = 0; j < 4; ++j)
      b[j] = *(const bf16x8*)(Bs + (wx * 64 + j * 16 + fr) * 64 + swz);

#pragma unroll
    for (int i = 0; i < 4; ++i)
#pragma unroll
      for (int j = 0; j < 4; ++j)
        acc[i][j] = __builtin_amdgcn_mfma_f32_16x16x32_bf16(a[i], b[j], acc[i][j], 0, 0, 0);
    __syncthreads();
  }

  const int ccol = lane & 15;
  const int crow = (lane >> 4) * 4;
#pragma unroll
  for (int i = 0; i < 4; ++i) {
    const int m = m0 + wy * 64 + i * 16 + crow;
#pragma unroll
    for (int j = 0; j < 4; ++j) {
      const int n = n0 + wx * 64 + j * 16 + ccol;
      if (n >= nvalid) continue;
      const float bv = bias[n];
#pragma unroll
      for (int r = 0; r < 4; ++r) {
        Cf[(size_t)(m + r) * ldc + n] = acc[i][j][r] + bv;
      }
    }
  }
}

extern "C" void kernel_launch(void* const* d_in, const int* in_sizes, int n_in,
                              void* d_out, int out_size, void* d_ws, size_t ws_size,
                              hipStream_t stream) {
  const float* x  = (const float*)d_in[0];   // [8192,4096]
  const float* w1 = (const float*)d_in[1];   // [4096,4096]
  const float* b1 = (const float*)d_in[2];   // [4096]
  const float* w2 = (const float*)d_in[3];   // [4096,4096]
  const float* b2 = (const float*)d_in[4];   // [4096]
  const float* w3 = (const float*)d_in[5];   // [1000,4096]
  const float* b3 = (const float*)d_in[6];   // [1000]

  const int Mb = 8192, H = 4096, C = 1000, Cpad = 1024;
  const int Kb = H / 2;                      // packed fp4 bytes per row

  // workspace layout (152 MB used):
  //   [0,16M)    xp   fp4-packed sign(x)       [8192,2048B]
  //   [16,24M)   w1p  fp4-packed sign(w1)      [4096,2048B]
  //   [24,32M)   w2p  fp4-packed sign(w2)      [4096,2048B]
  //   [32,40M)   w3b  bf16 [1024,4096] padded
  //   [40,72M)   a1   i8   [8192,4096]
  //   [72,88M)   a1p  fp4-packed a1            [8192,2048B]
  //   [88,152M)  a2   bf16 [8192,4096]
  char* ws = (char*)d_ws;
  unsigned*       xp  = (unsigned*)(ws);
  unsigned*       w1p = (unsigned*)(ws + (size_t)16777216);
  unsigned*       w2p = (unsigned*)(ws + (size_t)25165824);
  __hip_bfloat16* w3b = (__hip_bfloat16*)(ws + (size_t)33554432);
  char*           a1  = ws + (size_t)41943040;
  unsigned*       a1p = (unsigned*)(ws + (size_t)75497472);
  __hip_bfloat16* a2  = (__hip_bfloat16*)(ws + (size_t)92274688);

  sign_pack_fp4<<<(Mb * H / 8 + 255) / 256, 256, 0, stream>>>(x,  xp,  Mb * H / 8);
  sign_pack_fp4<<<(H * H / 8 + 255) / 256, 256, 0, stream>>>(w1, w1p, H * H / 8);
  sign_pack_fp4<<<(H * H / 8 + 255) / 256, 256, 0, stream>>>(w2, w2p, H * H / 8);
  w3_cast<<<(Cpad * H / 4 + 255) / 256, 256, 0, stream>>>(w3, w3b, C);

  dim3 blk(256);
  // layer 1: a1 = sign(sign(x) @ sign(w1)^T + b1)   [exact, MX-fp4]
  gemm_fp4<0><<<dim3(H / BN, Mb / BM), blk, 0, stream>>>(
      (const unsigned char*)xp, (const unsigned char*)w1p, b1, a1, nullptr, Kb, H);
  // repack ternary a1 (i8) -> fp4 for layer 2
  repack_i8_fp4<<<(Mb * H / 8 + 255) / 256, 256, 0, stream>>>(a1, a1p, Mb * H / 8);
  // layer 2: a2 = sign(a1 @ sign(w2)^T + b2)        [exact, MX-fp4]
  gemm_fp4<1><<<dim3(H / BN, Mb / BM), blk, 0, stream>>>(
      (const unsigned char*)a1p, (const unsigned char*)w2p, b2, nullptr, a2, Kb, H);
  // layer 3: out = a2 @ w3^T + b3                    [bf16-rounded w3]
  gemm_bt<<<dim3(Cpad / BN, Mb / BM), blk, 0, stream>>>(a2, w3b, b3, (float*)d_out, H, C, C);
}